// Round 3
// baseline (560.009 us; speedup 1.0000x reference)
//
#include <hip/hip_runtime.h>
#include <hip/hip_bf16.h>
#include <cstdint>

// B=32,C=32,V=1024,L=13; 3 supports x order 2; C_IN=224, C_OUT=64.
//  Arena (d_out): block0 = x-T [n2,v] bf16; block1 = Abf; block2 = AT2.
//  Ht (ws): [m=(b*1024+v)*13+l, cc=224] bf16
//  h2 = A^2 x: AT2 = AT*A (small GEMM), then ONE 6-z 256^2 4-phase GEMM.
//  k_gemm256: 256x256, BK=64 (2 k-halves), 8 waves (2Mx4N), 128KB dbuf LDS,
//    counted vmcnt(10) at phases 1&3 (5-7 phase slack/load), 1 barrier/phase,
//    setprio around MFMA, XCD-chunked swizzle, NT register->global epilogue.
//  k_fc: A streamed global->VGPR depth-2 prefetch, W-only LDS, NT loads/stores.

#define SZE 13631488ull        // elems per [13312,1024] block
#define OFF_AT  190840832ull   // Ht bytes = 425984*224*2
#define OFF_WB  197132288ull   // OFF_AT + 3*1024*1024*2
#define WS_NEED 197160960ull   // OFF_WB + 64*224*2

typedef __attribute__((ext_vector_type(8))) short short8;
typedef __attribute__((ext_vector_type(4))) float f32x4;

__device__ __forceinline__ unsigned short f2b(float f) {
    unsigned int u = __builtin_bit_cast(unsigned int, f);
    u += 0x7FFFu + ((u >> 16) & 1u);          // round-to-nearest-even
    return (unsigned short)(u >> 16);
}

__device__ __forceinline__ void gl2lds16(const unsigned short* g, unsigned short* l) {
    __builtin_amdgcn_global_load_lds(
        (__attribute__((address_space(1))) void*)(g),
        (__attribute__((address_space(3))) void*)(l), 16, 0, 0);
}

__device__ __forceinline__ void nt_st8(unsigned short* p, float a, float b, float c, float d) {
    unsigned long long pk = (unsigned long long)f2b(a)
        | ((unsigned long long)f2b(b) << 16)
        | ((unsigned long long)f2b(c) << 32)
        | ((unsigned long long)f2b(d) << 48);
    __builtin_nontemporal_store(pk, (unsigned long long*)p);
}

// ---------- fused prep: x[b,c,v,l] f32 -> T rows (block0) + Ht cc0..31 ----------
__global__ __launch_bounds__(256) void k_prep(const float* __restrict__ x,
                                              unsigned short* __restrict__ T,
                                              unsigned short* __restrict__ Ht) {
    __shared__ unsigned short sb[32 * 840];   // [c][e=v*13+l], 832 padded to 840
    const int b = blockIdx.x >> 4, vc = blockIdx.x & 15;
    const int t = threadIdx.x;
    const float4* xb = (const float4*)x;
    for (int it = 0; it < 26; ++it) {
        int q = it * 256 + t;                 // 6656 = 32c * 208f4
        int c = q / 208, f = q - c * 208;
        float4 u = xb[(size_t)(b * 32 + c) * 3328 + vc * 208 + f];
        ushort4 pk; pk.x = f2b(u.x); pk.y = f2b(u.y); pk.z = f2b(u.z); pk.w = f2b(u.w);
        *(ushort4*)(sb + c * 840 + f * 4) = pk;
    }
    __syncthreads();
    unsigned short* Tb = T + (size_t)b * 13 * 32 * 1024 + (size_t)vc * 64;
    for (int it = 0; it < 26; ++it) {
        int q = it * 256 + t;                 // 6656 = 13l * 32c * 16sg
        int l = q >> 9, r = q & 511, c = r >> 4, sg = r & 15;
        const unsigned short* src = sb + c * 840 + l;
        ushort4 pk;
        pk.x = src[(sg * 4 + 0) * 13];
        pk.y = src[(sg * 4 + 1) * 13];
        pk.z = src[(sg * 4 + 2) * 13];
        pk.w = src[(sg * 4 + 3) * 13];
        *(ushort4*)(Tb + (size_t)(l * 32 + c) * 1024 + sg * 4) = pk;   // cached: gemm reads it
    }
    unsigned short* Hb = Ht + ((size_t)b * 13312 + (size_t)vc * 832) * 224;
    for (int it = 0; it < 26; ++it) {
        int q = it * 256 + t;                 // 6656 = 64v * 13l * 8cs
        int v = q / 104, r = q - v * 104, l = r >> 3, cs = r & 7;
        const unsigned short* src = sb + v * 13 + l;
        ushort4 pk;
        pk.x = src[(cs * 4 + 0) * 840];
        pk.y = src[(cs * 4 + 1) * 840];
        pk.z = src[(cs * 4 + 2) * 840];
        pk.w = src[(cs * 4 + 3) * 840];
        __builtin_nontemporal_store(__builtin_bit_cast(unsigned long long, pk),
            (unsigned long long*)(Hb + (size_t)(v * 13 + l) * 224 + cs * 4));
    }
}

// ---------- prep A: A[v,w] f32 -> AT[w,v] bf16 + Abf[v,w] bf16, 3 mats ----------
__global__ __launch_bounds__(256) void k_prep_A(const float* __restrict__ A0,
                                                const float* __restrict__ A1,
                                                const float* __restrict__ A2,
                                                unsigned short* __restrict__ AT,
                                                unsigned short* __restrict__ Abf) {
    const float* A = blockIdx.z == 0 ? A0 : blockIdx.z == 1 ? A1 : A2;
    unsigned short* D = AT + (size_t)blockIdx.z * 1024 * 1024;
    unsigned short* D2 = Abf + (size_t)blockIdx.z * 1024 * 1024;
    __shared__ float tile[32][33];
    int v0 = blockIdx.y * 32, w0 = blockIdx.x * 32;
    int c = threadIdx.x & 31, r = threadIdx.x >> 5;
    for (int p = 0; p < 4; ++p) {
        int rr = r + p * 8;
        float val = A[(size_t)(v0 + rr) * 1024 + w0 + c];
        tile[rr][c] = val;
        D2[(size_t)(v0 + rr) * 1024 + w0 + c] = f2b(val);
    }
    __syncthreads();
    for (int p = 0; p < 4; ++p) {
        int rr = r + p * 8;
        D[(size_t)(w0 + rr) * 1024 + v0 + c] = f2b(tile[c][rr]);
    }
}

// ---------- prep W: W[o,cc] f32 -> Wb[o,cc] bf16 ----------
__global__ __launch_bounds__(256) void k_prep_W(const float* __restrict__ W,
                                                unsigned short* __restrict__ Wb) {
    int idx = blockIdx.x * 256 + threadIdx.x;  // 14336 = 56*256
    Wb[idx] = f2b(W[idx]);
}

// ---------- small GEMM (128^2 tiles) kept for the AT2 build ----------
__global__ __launch_bounds__(256) void k_gemm(const unsigned short* __restrict__ Xb, long xz,
                                              const unsigned short* __restrict__ P0,
                                              const unsigned short* __restrict__ P1,
                                              unsigned short* __restrict__ Tout, long tz,
                                              unsigned short* __restrict__ Ht, int doT) {
    __shared__ union {
        struct { unsigned short xs[8192]; unsigned short ps[8192]; } s;
        unsigned short cs[128 * 132];
    } lds;
    const int z = blockIdx.z;
    const unsigned short* X = Xb + (size_t)z * (size_t)xz;
    const unsigned short* P = (z < 3) ? P0 + (size_t)z * 1048576u
                                      : P1 + (size_t)(z - 3) * 1048576u;
    const int i0 = blockIdx.x * 128;
    const int j0 = blockIdx.y * 128;
    const int t = threadIdx.x;
    const int lane = t & 63, wave = t >> 6;
    const int l16 = lane & 15, quad = lane >> 4;
    const int wi = (wave >> 1) * 64, wj = (wave & 1) * 64;

    f32x4 acc[4][4] = {};

    const int row = t >> 2, seg = t & 3;
    const unsigned short* xg0 = X + (size_t)(i0 + row) * 1024 + seg * 8;
    const unsigned short* xg1 = xg0 + (size_t)64 * 1024;
    const unsigned short* pg0 = P + (size_t)(j0 + row) * 1024 + seg * 8;
    const unsigned short* pg1 = pg0 + (size_t)64 * 1024;
    unsigned short* lx0 = lds.s.xs + t * 8;
    unsigned short* lp0 = lds.s.ps + t * 8;

    for (int kt = 0; kt < 16; ++kt) {
        const int ko = kt * 64;
        gl2lds16(xg0 + ko,      lx0);
        gl2lds16(xg1 + ko,      lx0 + 2048);
        gl2lds16(xg0 + ko + 32, lx0 + 4096);
        gl2lds16(xg1 + ko + 32, lx0 + 6144);
        gl2lds16(pg0 + ko,      lp0);
        gl2lds16(pg1 + ko,      lp0 + 2048);
        gl2lds16(pg0 + ko + 32, lp0 + 4096);
        gl2lds16(pg1 + ko + 32, lp0 + 6144);
        __syncthreads();
#pragma unroll
        for (int p = 0; p < 2; ++p) {
            short8 a[4], b[4];
#pragma unroll
            for (int mi = 0; mi < 4; ++mi)
                a[mi] = *(const short8*)(lds.s.xs + p * 4096 + (wi + mi * 16 + l16) * 32 + quad * 8);
#pragma unroll
            for (int nj = 0; nj < 4; ++nj)
                b[nj] = *(const short8*)(lds.s.ps + p * 4096 + (wj + nj * 16 + l16) * 32 + quad * 8);
#pragma unroll
            for (int mi = 0; mi < 4; ++mi)
#pragma unroll
                for (int nj = 0; nj < 4; ++nj)
                    acc[mi][nj] = __builtin_amdgcn_mfma_f32_16x16x32_bf16(a[mi], b[nj], acc[mi][nj], 0, 0, 0);
        }
        __syncthreads();
    }

    if (doT) {
#pragma unroll
        for (int mi = 0; mi < 4; ++mi)
#pragma unroll
            for (int nj = 0; nj < 4; ++nj)
#pragma unroll
                for (int r = 0; r < 4; ++r)
                    lds.cs[(wi + mi * 16 + quad * 4 + r) * 132 + (wj + nj * 16 + l16)] =
                        f2b(acc[mi][nj][r]);
        __syncthreads();
        unsigned short* O = Tout + (size_t)z * (size_t)tz;
#pragma unroll
        for (int rep = 0; rep < 8; ++rep) {
            int q = rep * 256 + t;
            int rr = q >> 4, sg = q & 15;
            *(uint4*)(O + (size_t)(i0 + rr) * 1024 + j0 + sg * 8) =
                *(const uint4*)(lds.cs + rr * 132 + sg * 8);
        }
    }
}

// ---------- big hop GEMM: 256^2 tile, 4-phase counted-vmcnt schedule ----------
// C[n2,w] = sum_v X[n2,v]*P[w,v].  M=13312, N=1024, K=1024, 6 z.
// Half-tile H = 4*kt + h; h: 0=A-k0, 1=B-k0, 2=A-k1, 3=B-k1.  Issue plan:
// tile kt phases 0..3 issue H = 4kt+7..4kt+10.  Waits (derived pairwise):
//   p1: vmcnt(10) => this tile's h3,h2 landed (needed p2/p3)
//   p3: vmcnt(10) => next tile's h0,h1 landed (needed p0/p1)
// Tail: p1@kt14 vmcnt(8); p3@kt14 vmcnt(0); kt15 no waits.
// One barrier per phase (trailing); per-wave vmcnt before it globalizes.
__global__ __launch_bounds__(512, 2) void k_gemm256(
        const unsigned short* __restrict__ Xb,
        const unsigned short* __restrict__ P0,
        const unsigned short* __restrict__ P1,
        unsigned short* __restrict__ Ht) {
    __shared__ unsigned short lds[65536];     // 128 KB
    // XCD-chunked bijective swizzle: 1248 blocks = 8 * 156
    const int flat = blockIdx.x + 52 * (blockIdx.y + 4 * blockIdx.z);
    const int nf = (flat & 7) * 156 + (flat >> 3);
    const int z = nf / 208;
    const int rem = nf - z * 208;
    const int i0 = (rem % 52) * 256;
    const int j0 = (rem / 52) * 256;
    const unsigned short* P = (z < 3) ? P0 + (size_t)z * 1048576u
                                      : P1 + (size_t)(z - 3) * 1048576u;
    const int t = threadIdx.x;
    const int lane = t & 63;
    const int l16 = lane & 15, quad = lane >> 4;
    const int wave = t >> 6, wm = wave >> 2, wn = wave & 3;

    const unsigned short* pa0 = Xb + (size_t)(i0 + (t >> 2)) * 1024 + (t & 3) * 8;
    const unsigned short* pb0 = P  + (size_t)(j0 + (t >> 2)) * 1024 + (t & 3) * 8;

    const int aoff = (wm * 128 + l16) * 32 + quad * 8;
    const int boff = 16384 + (wn * 64 + l16) * 32 + quad * 8;

    auto stage = [&](int H) {
        if (H >= 64) return;
        const int kt = H >> 2, h = H & 3;
        const int ks = h >> 1;
        const unsigned short* s = ((h & 1) ? pb0 : pa0) + kt * 64 + ks * 32;
        unsigned short* d = lds + (kt & 1) * 32768 + (h & 1) * 16384 + ks * 8192 + t * 8;
        gl2lds16(s, d);
        gl2lds16(s + 131072, d + 4096);       // +128 rows * 1024
    };

    f32x4 acc[8][4] = {};

#pragma unroll
    for (int H = 0; H < 7; ++H) stage(H);     // tile0 (4) + tile1 h0..h2
    asm volatile("s_waitcnt vmcnt(6)" ::: "memory");   // tile0 fully landed (own)
    __builtin_amdgcn_s_barrier();                      // ... for all waves

#pragma unroll 1
    for (int kt = 0; kt < 16; ++kt) {
        const int base = (kt & 1) * 32768;
        const int P4 = kt * 4;
        short8 a[8], b0, b1;

        // ---- phase 0: ks=0, nj 0..1 ----
#pragma unroll
        for (int mi = 0; mi < 8; ++mi)
            a[mi] = *(const short8*)(lds + base + aoff + mi * 512);
        b0 = *(const short8*)(lds + base + boff);
        b1 = *(const short8*)(lds + base + boff + 512);
        stage(P4 + 7);                        // tile kt+1 B-k1 (other buffer)
        __builtin_amdgcn_sched_barrier(0);
        asm volatile("s_waitcnt lgkmcnt(0)" ::: "memory");
        __builtin_amdgcn_sched_barrier(0);
        __builtin_amdgcn_s_setprio(1);
#pragma unroll
        for (int mi = 0; mi < 8; ++mi) {
            acc[mi][0] = __builtin_amdgcn_mfma_f32_16x16x32_bf16(a[mi], b0, acc[mi][0], 0, 0, 0);
            acc[mi][1] = __builtin_amdgcn_mfma_f32_16x16x32_bf16(a[mi], b1, acc[mi][1], 0, 0, 0);
        }
        __builtin_amdgcn_s_setprio(0);
        __builtin_amdgcn_sched_barrier(0);
        __builtin_amdgcn_s_barrier();

        // ---- phase 1: ks=0, nj 2..3 (reuse a) ----
        b0 = *(const short8*)(lds + base + boff + 2 * 512);
        b1 = *(const short8*)(lds + base + boff + 3 * 512);
        stage(P4 + 8);                        // tile kt+2 A-k0 (cur buf, dead after p0)
        if (kt < 14)       asm volatile("s_waitcnt vmcnt(10)" ::: "memory");
        else if (kt == 14) asm volatile("s_waitcnt vmcnt(8)"  ::: "memory");
        __builtin_amdgcn_sched_barrier(0);
        asm volatile("s_waitcnt lgkmcnt(0)" ::: "memory");
        __builtin_amdgcn_sched_barrier(0);
        __builtin_amdgcn_s_setprio(1);
#pragma unroll
        for (int mi = 0; mi < 8; ++mi) {
            acc[mi][2] = __builtin_amdgcn_mfma_f32_16x16x32_bf16(a[mi], b0, acc[mi][2], 0, 0, 0);
            acc[mi][3] = __builtin_amdgcn_mfma_f32_16x16x32_bf16(a[mi], b1, acc[mi][3], 0, 0, 0);
        }
        __builtin_amdgcn_s_setprio(0);
        __builtin_amdgcn_sched_barrier(0);
        __builtin_amdgcn_s_barrier();

        // ---- phase 2: ks=1, nj 0..1 ----
#pragma unroll
        for (int mi = 0; mi < 8; ++mi)
            a[mi] = *(const short8*)(lds + base + 8192 + aoff + mi * 512);
        b0 = *(const short8*)(lds + base + 8192 + boff);
        b1 = *(const short8*)(lds + base + 8192 + boff + 512);
        stage(P4 + 9);                        // tile kt+2 B-k0 (dead after p1)
        __builtin_amdgcn_sched_barrier(0);
        asm volatile("s_waitcnt lgkmcnt(0)" ::: "memory");
        __builtin_amdgcn_sched_barrier(0);
        __builtin_amdgcn_s_setprio(1);
#pragma unroll
        for (int mi = 0; mi < 8; ++mi) {
            acc[mi][0] = __builtin_amdgcn_mfma_f32_16x16x32_bf16(a[mi], b0, acc[mi][0], 0, 0, 0);
            acc[mi][1] = __builtin_amdgcn_mfma_f32_16x16x32_bf16(a[mi], b1, acc[mi][1], 0, 0, 0);
        }
        __builtin_amdgcn_s_setprio(0);
        __builtin_amdgcn_sched_barrier(0);
        __builtin_amdgcn_s_barrier();

        // ---- phase 3: ks=1, nj 2..3 (reuse a) ----
        b0 = *(const short8*)(lds + base + 8192 + boff + 2 * 512);
        b1 = *(const short8*)(lds + base + 8192 + boff + 3 * 512);
        stage(P4 + 10);                       // tile kt+2 A-k1 (dead after p2)
        if (kt < 14)       asm volatile("s_waitcnt vmcnt(10)" ::: "memory");
        else if (kt == 14) asm volatile("s_waitcnt vmcnt(0)"  ::: "memory");
        __builtin_amdgcn_sched_barrier(0);
        asm volatile("s_waitcnt lgkmcnt(0)" ::: "memory");
        __builtin_amdgcn_sched_barrier(0);
        __builtin_amdgcn_s_setprio(1);
#pragma unroll
        for (int mi = 0; mi < 8; ++mi) {
            acc[mi][2] = __builtin_amdgcn_mfma_f32_16x16x32_bf16(a[mi], b0, acc[mi][2], 0, 0, 0);
            acc[mi][3] = __builtin_amdgcn_mfma_f32_16x16x32_bf16(a[mi], b1, acc[mi][3], 0, 0, 0);
        }
        __builtin_amdgcn_s_setprio(0);
        __builtin_amdgcn_sched_barrier(0);
        __builtin_amdgcn_s_barrier();
    }

    // ---- epilogue: registers -> Ht, non-temporal (write-once, no reuse) ----
    const int cc0 = (z < 3) ? 32 + 64 * z : 64 * (z - 2);
    const int wc = j0 + wn * 64 + l16;
#pragma unroll
    for (int mi = 0; mi < 8; ++mi) {
        int p = (i0 >> 5) + wm * 4 + (mi >> 1);   // slab = b*13 + l
        int b = p / 13, l = p - b * 13;
        int cc = cc0 + (mi & 1) * 16 + quad * 4;
#pragma unroll
        for (int nj = 0; nj < 4; ++nj) {
            int w = wc + nj * 16;
            size_t m = (size_t)b * 13312 + (size_t)w * 13 + l;
            nt_st8(Ht + m * 224 + cc,
                   acc[mi][nj][0], acc[mi][nj][1], acc[mi][nj][2], acc[mi][nj][3]);
        }
    }
}

// ---------- final conv: y[m,o] = sum_cc Ht[m,cc]*W[o,cc] + bias ----------
// A streamed global->VGPR with depth-2 prefetch, NT loads (read-once) and
// NT stores; W-only LDS; per-wave-independent 13x(16x64) tiles.
__global__ __launch_bounds__(256) void k_fc(const unsigned short* __restrict__ Ht,
                                            const unsigned short* __restrict__ Wb,
                                            const float* __restrict__ bias,
                                            float* __restrict__ y) {
    __shared__ unsigned short sw[64 * 232];
    const int bid = blockIdx.x;               // 512 = 32 b * 16 vb(64 v)
    const int b = bid >> 4, v0 = (bid & 15) * 64;
    const int t = threadIdx.x;
    const int lane = t & 63, wave = t >> 6;   // 4 waves
    const int l16 = lane & 15, quad = lane >> 4;

    for (int it = 0; it < 7; ++it) {
        int q = it * 256 + t;                 // 1792 uint4 = 64o x 28sg
        int o = q / 28, sg = q % 28;
        *(uint4*)(sw + o * 232 + sg * 8) = *(const uint4*)(Wb + o * 224 + sg * 8);
    }

    const size_t mw = (size_t)b * 13312 + (size_t)v0 * 13 + wave * 208;
    const unsigned short* ag = Ht + (mw + l16) * 224 + quad * 8;
    float* yb = y + (size_t)b * 851968 + (size_t)v0 * 13 + wave * 208 + quad * 4;

    float bv[4];
#pragma unroll
    for (int nj = 0; nj < 4; ++nj) bv[nj] = bias[nj * 16 + l16];

    short8 c0[7], c1[7];
#pragma unroll
    for (int kk = 0; kk < 7; ++kk) {
        c0[kk] = __builtin_nontemporal_load((const short8*)(ag + kk * 32));
        c1[kk] = __builtin_nontemporal_load((const short8*)(ag + 3584 + kk * 32));
    }
    __syncthreads();

    auto body = [&](int mf, short8 (&cur)[7]) {
        short8 nxt[7];
        const bool pf = (mf + 2 < 13);
        if (pf) {
#pragma unroll
            for (int kk = 0; kk < 7; ++kk)
                nxt[kk] = __builtin_nontemporal_load(
                    (const short8*)(ag + (size_t)(mf + 2) * 3584 + kk * 32));
        }
        f32x4 acc[4];
#pragma unroll
        for (int nj = 0; nj < 4; ++nj) acc[nj] = (f32x4){bv[nj], bv[nj], bv[nj], bv[nj]};
#pragma unroll
        for (int kk = 0; kk < 7; ++kk)
#pragma unroll
            for (int nj = 0; nj < 4; ++nj) {
                short8 bf = *(const short8*)(sw + (nj * 16 + l16) * 232 + kk * 32 + quad * 8);
                acc[nj] = __builtin_amdgcn_mfma_f32_16x16x32_bf16(cur[kk], bf, acc[nj], 0, 0, 0);
            }
#pragma unroll
        for (int nj = 0; nj < 4; ++nj)
            __builtin_nontemporal_store(acc[nj],
                (f32x4*)(yb + (size_t)(nj * 16 + l16) * 13312 + mf * 16));
        if (pf) {
#pragma unroll
            for (int kk = 0; kk < 7; ++kk) cur[kk] = nxt[kk];
        }
    };
#pragma unroll
    for (int mf = 0; mf < 13; ++mf) {
        if (mf & 1) body(mf, c1); else body(mf, c0);
    }
}

extern "C" void kernel_launch(void* const* d_in, const int* in_sizes, int n_in,
                              void* d_out, int out_size, void* d_ws, size_t ws_size,
                              hipStream_t stream) {
    const float* x    = (const float*)d_in[0];
    const float* A0   = (const float*)d_in[1];
    const float* A1   = (const float*)d_in[2];
    const float* A2   = (const float*)d_in[3];
    const float* W    = (const float*)d_in[4];
    const float* bias = (const float*)d_in[5];

    if (ws_size < WS_NEED) return;

    unsigned short* Ht = (unsigned short*)d_ws;
    unsigned short* AT = (unsigned short*)((char*)d_ws + OFF_AT);
    unsigned short* Wb = (unsigned short*)((char*)d_ws + OFF_WB);
    unsigned short* Tarena = (unsigned short*)d_out;   // block0: x-T
    unsigned short* Abf = Tarena + SZE;                // arena block1 (free)
    unsigned short* AT2 = Tarena + 2 * SZE;            // arena block2 (free)

    k_prep<<<512, 256, 0, stream>>>(x, Tarena, Ht);
    k_prep_A<<<dim3(32, 32, 3), 256, 0, stream>>>(A0, A1, A2, AT, Abf);
    k_prep_W<<<56, 256, 0, stream>>>(W, Wb);
    // AT2[w,v] = sum_u AT[w,u]*Abf[v,u] = (A*A)^T, bf16
    k_gemm<<<dim3(8, 8, 3), 256, 0, stream>>>(AT, 1048576L, Abf, Abf,
                                              AT2, 1048576L, nullptr, 1);
    // all 6 hops from x-T in one 256^2 4-phase launch
    k_gemm256<<<dim3(52, 4, 6), 512, 0, stream>>>(Tarena, AT, AT2, Ht);
    k_fc<<<512, 256, 0, stream>>>(Ht, Wb, bias, (float*)d_out);
}

// Round 4
// 464.859 us; speedup vs baseline: 1.2047x; 1.2047x over previous
//
#include <hip/hip_runtime.h>
#include <hip/hip_bf16.h>
#include <cstdint>

// B=32,C=32,V=1024,L=13; 3 supports x order 2; C_IN=224, C_OUT=64.
//  Arena (d_out): block0 = x-T [n2,v] bf16; block1 = Abf; block2 = AT2.
//  Ht (ws): [m=(b*1024+v)*13+l, cc=224] bf16
//  h2 = A^2 x: AT2 = AT*A (small GEMM), then ONE 256^2 4-phase GEMM over all
//  24 (j0,z) combos x 52 i0.  Dispatch is i0-major (blockIdx.x = 24 combos,
//  blockIdx.y = i0) so concurrent blocks share A panels and keep the whole
//  B set (12 MB) L3-hot -> x-T and AT/AT2 fetched ~once from HBM.
//  k_gemm256: 256x256, BK=64 (2 k-halves), 8 waves (2Mx4N), 128KB dbuf LDS,
//    counted vmcnt(6) once per K-tile (3-phase slack/load), setprio, cached
//    register->global Ht epilogue (NT stores proved RMW-toxic in round 3).
//  k_fc: A streamed global->VGPR depth-2 prefetch, W-only LDS, 4 waves/block
//    (m-half x o-half) x 1024 blocks = 16 waves/CU for latency hiding.

#define SZE 13631488ull        // elems per [13312,1024] block
#define OFF_AT  190840832ull   // Ht bytes = 425984*224*2
#define OFF_WB  197132288ull   // OFF_AT + 3*1024*1024*2
#define WS_NEED 197160960ull   // OFF_WB + 64*224*2

typedef __attribute__((ext_vector_type(8))) short short8;
typedef __attribute__((ext_vector_type(4))) float f32x4;

__device__ __forceinline__ unsigned short f2b(float f) {
    unsigned int u = __builtin_bit_cast(unsigned int, f);
    u += 0x7FFFu + ((u >> 16) & 1u);          // round-to-nearest-even
    return (unsigned short)(u >> 16);
}

__device__ __forceinline__ void gl2lds16(const unsigned short* g, unsigned short* l) {
    __builtin_amdgcn_global_load_lds(
        (__attribute__((address_space(1))) void*)(g),
        (__attribute__((address_space(3))) void*)(l), 16, 0, 0);
}

// ---------- fused prep: x[b,c,v,l] f32 -> T rows (block0) + Ht cc0..31 ----------
__global__ __launch_bounds__(256) void k_prep(const float* __restrict__ x,
                                              unsigned short* __restrict__ T,
                                              unsigned short* __restrict__ Ht) {
    __shared__ unsigned short sb[32 * 840];   // [c][e=v*13+l], 832 padded to 840
    const int b = blockIdx.x >> 4, vc = blockIdx.x & 15;
    const int t = threadIdx.x;
    const float4* xb = (const float4*)x;
    for (int it = 0; it < 26; ++it) {
        int q = it * 256 + t;                 // 6656 = 32c * 208f4
        int c = q / 208, f = q - c * 208;
        float4 u = xb[(size_t)(b * 32 + c) * 3328 + vc * 208 + f];
        ushort4 pk; pk.x = f2b(u.x); pk.y = f2b(u.y); pk.z = f2b(u.z); pk.w = f2b(u.w);
        *(ushort4*)(sb + c * 840 + f * 4) = pk;
    }
    __syncthreads();
    unsigned short* Tb = T + (size_t)b * 13 * 32 * 1024 + (size_t)vc * 64;
    for (int it = 0; it < 26; ++it) {
        int q = it * 256 + t;                 // 6656 = 13l * 32c * 16sg
        int l = q >> 9, r = q & 511, c = r >> 4, sg = r & 15;
        const unsigned short* src = sb + c * 840 + l;
        ushort4 pk;
        pk.x = src[(sg * 4 + 0) * 13];
        pk.y = src[(sg * 4 + 1) * 13];
        pk.z = src[(sg * 4 + 2) * 13];
        pk.w = src[(sg * 4 + 3) * 13];
        *(ushort4*)(Tb + (size_t)(l * 32 + c) * 1024 + sg * 4) = pk;
    }
    unsigned short* Hb = Ht + ((size_t)b * 13312 + (size_t)vc * 832) * 224;
    for (int it = 0; it < 26; ++it) {
        int q = it * 256 + t;                 // 6656 = 64v * 13l * 8cs
        int v = q / 104, r = q - v * 104, l = r >> 3, cs = r & 7;
        const unsigned short* src = sb + v * 13 + l;
        ushort4 pk;
        pk.x = src[(cs * 4 + 0) * 840];
        pk.y = src[(cs * 4 + 1) * 840];
        pk.z = src[(cs * 4 + 2) * 840];
        pk.w = src[(cs * 4 + 3) * 840];
        *(ushort4*)(Hb + (size_t)(v * 13 + l) * 224 + cs * 4) = pk;
    }
}

// ---------- prep A: A[v,w] f32 -> AT[w,v] bf16 + Abf[v,w] bf16, 3 mats ----------
__global__ __launch_bounds__(256) void k_prep_A(const float* __restrict__ A0,
                                                const float* __restrict__ A1,
                                                const float* __restrict__ A2,
                                                unsigned short* __restrict__ AT,
                                                unsigned short* __restrict__ Abf) {
    const float* A = blockIdx.z == 0 ? A0 : blockIdx.z == 1 ? A1 : A2;
    unsigned short* D = AT + (size_t)blockIdx.z * 1024 * 1024;
    unsigned short* D2 = Abf + (size_t)blockIdx.z * 1024 * 1024;
    __shared__ float tile[32][33];
    int v0 = blockIdx.y * 32, w0 = blockIdx.x * 32;
    int c = threadIdx.x & 31, r = threadIdx.x >> 5;
    for (int p = 0; p < 4; ++p) {
        int rr = r + p * 8;
        float val = A[(size_t)(v0 + rr) * 1024 + w0 + c];
        tile[rr][c] = val;
        D2[(size_t)(v0 + rr) * 1024 + w0 + c] = f2b(val);
    }
    __syncthreads();
    for (int p = 0; p < 4; ++p) {
        int rr = r + p * 8;
        D[(size_t)(w0 + rr) * 1024 + v0 + c] = f2b(tile[c][rr]);
    }
}

// ---------- prep W: W[o,cc] f32 -> Wb[o,cc] bf16 ----------
__global__ __launch_bounds__(256) void k_prep_W(const float* __restrict__ W,
                                                unsigned short* __restrict__ Wb) {
    int idx = blockIdx.x * 256 + threadIdx.x;  // 14336 = 56*256
    Wb[idx] = f2b(W[idx]);
}

// ---------- small GEMM (128^2 tiles) kept for the AT2 build ----------
__global__ __launch_bounds__(256) void k_gemm(const unsigned short* __restrict__ Xb, long xz,
                                              const unsigned short* __restrict__ P0,
                                              const unsigned short* __restrict__ P1,
                                              unsigned short* __restrict__ Tout, long tz,
                                              unsigned short* __restrict__ Ht, int doT) {
    __shared__ union {
        struct { unsigned short xs[8192]; unsigned short ps[8192]; } s;
        unsigned short cs[128 * 132];
    } lds;
    const int z = blockIdx.z;
    const unsigned short* X = Xb + (size_t)z * (size_t)xz;
    const unsigned short* P = (z < 3) ? P0 + (size_t)z * 1048576u
                                      : P1 + (size_t)(z - 3) * 1048576u;
    const int i0 = blockIdx.x * 128;
    const int j0 = blockIdx.y * 128;
    const int t = threadIdx.x;
    const int lane = t & 63, wave = t >> 6;
    const int l16 = lane & 15, quad = lane >> 4;
    const int wi = (wave >> 1) * 64, wj = (wave & 1) * 64;

    f32x4 acc[4][4] = {};

    const int row = t >> 2, seg = t & 3;
    const unsigned short* xg0 = X + (size_t)(i0 + row) * 1024 + seg * 8;
    const unsigned short* xg1 = xg0 + (size_t)64 * 1024;
    const unsigned short* pg0 = P + (size_t)(j0 + row) * 1024 + seg * 8;
    const unsigned short* pg1 = pg0 + (size_t)64 * 1024;
    unsigned short* lx0 = lds.s.xs + t * 8;
    unsigned short* lp0 = lds.s.ps + t * 8;

    for (int kt = 0; kt < 16; ++kt) {
        const int ko = kt * 64;
        gl2lds16(xg0 + ko,      lx0);
        gl2lds16(xg1 + ko,      lx0 + 2048);
        gl2lds16(xg0 + ko + 32, lx0 + 4096);
        gl2lds16(xg1 + ko + 32, lx0 + 6144);
        gl2lds16(pg0 + ko,      lp0);
        gl2lds16(pg1 + ko,      lp0 + 2048);
        gl2lds16(pg0 + ko + 32, lp0 + 4096);
        gl2lds16(pg1 + ko + 32, lp0 + 6144);
        __syncthreads();
#pragma unroll
        for (int p = 0; p < 2; ++p) {
            short8 a[4], b[4];
#pragma unroll
            for (int mi = 0; mi < 4; ++mi)
                a[mi] = *(const short8*)(lds.s.xs + p * 4096 + (wi + mi * 16 + l16) * 32 + quad * 8);
#pragma unroll
            for (int nj = 0; nj < 4; ++nj)
                b[nj] = *(const short8*)(lds.s.ps + p * 4096 + (wj + nj * 16 + l16) * 32 + quad * 8);
#pragma unroll
            for (int mi = 0; mi < 4; ++mi)
#pragma unroll
                for (int nj = 0; nj < 4; ++nj)
                    acc[mi][nj] = __builtin_amdgcn_mfma_f32_16x16x32_bf16(a[mi], b[nj], acc[mi][nj], 0, 0, 0);
        }
        __syncthreads();
    }

    if (doT) {
#pragma unroll
        for (int mi = 0; mi < 4; ++mi)
#pragma unroll
            for (int nj = 0; nj < 4; ++nj)
#pragma unroll
                for (int r = 0; r < 4; ++r)
                    lds.cs[(wi + mi * 16 + quad * 4 + r) * 132 + (wj + nj * 16 + l16)] =
                        f2b(acc[mi][nj][r]);
        __syncthreads();
        unsigned short* O = Tout + (size_t)z * (size_t)tz;
#pragma unroll
        for (int rep = 0; rep < 8; ++rep) {
            int q = rep * 256 + t;
            int rr = q >> 4, sg = q & 15;
            *(uint4*)(O + (size_t)(i0 + rr) * 1024 + j0 + sg * 8) =
                *(const uint4*)(lds.cs + rr * 132 + sg * 8);
        }
    }
}

// ---------- big hop GEMM: 256^2 tile, 4-phase counted-vmcnt schedule ----------
// C[n2,w] = sum_v X[n2,v]*P[w,v].  M=13312, N=1024, K=1024, 6 z.
// blockIdx.x = 24 (j0,z) combos (i0-major dispatch), blockIdx.y = i0/256.
// Half-tile H = 4*kt + h; h: 0=A-k0, 1=B-k0, 2=A-k1, 3=B-k1.  Tile kt's
// phases 0..3 issue H = 4kt+7..4kt+10 into provably-dead LDS regions; one
// vmcnt(6) in each tile's last phase guarantees tile kt+1 fully landed
// (every load gets >=3 phases of slack).  Drain vmcnt(0) only at kt=14.
__global__ __launch_bounds__(512, 2) void k_gemm256(
        const unsigned short* __restrict__ Xb,
        const unsigned short* __restrict__ P0,
        const unsigned short* __restrict__ P1,
        unsigned short* __restrict__ Ht) {
    __shared__ unsigned short lds[65536];     // 128 KB
    const int comb = blockIdx.x;              // 24 = 4 j0 * 6 z
    const int z = comb >> 2;
    const int j0 = (comb & 3) * 256;
    const int i0 = blockIdx.y * 256;
    const unsigned short* P = (z < 3) ? P0 + (size_t)z * 1048576u
                                      : P1 + (size_t)(z - 3) * 1048576u;
    const int t = threadIdx.x;
    const int lane = t & 63;
    const int l16 = lane & 15, quad = lane >> 4;
    const int wave = t >> 6, wm = wave >> 2, wn = wave & 3;

    const unsigned short* pa0 = Xb + (size_t)(i0 + (t >> 2)) * 1024 + (t & 3) * 8;
    const unsigned short* pb0 = P  + (size_t)(j0 + (t >> 2)) * 1024 + (t & 3) * 8;

    const int aoff = (wm * 128 + l16) * 32 + quad * 8;
    const int boff = 16384 + (wn * 64 + l16) * 32 + quad * 8;

    auto stage = [&](int H) {
        if (H >= 64) return;
        const int kt = H >> 2, h = H & 3;
        const int ks = h >> 1;
        const unsigned short* s = ((h & 1) ? pb0 : pa0) + kt * 64 + ks * 32;
        unsigned short* d = lds + (kt & 1) * 32768 + (h & 1) * 16384 + ks * 8192 + t * 8;
        gl2lds16(s, d);
        gl2lds16(s + 131072, d + 4096);       // +128 rows * 1024
    };

    f32x4 acc[8][4] = {};

#pragma unroll
    for (int H = 0; H < 7; ++H) stage(H);     // tile0 (4) + tile1 h0..h2
    asm volatile("s_waitcnt vmcnt(6)" ::: "memory");   // tile0 landed (own loads)
    __builtin_amdgcn_s_barrier();                      // ... for all waves

#pragma unroll 1
    for (int kt = 0; kt < 16; ++kt) {
        const int base = (kt & 1) * 32768;
        const int P4 = kt * 4;
        short8 a[8], b0, b1;

        // ---- phase 0: ks=0, nj 0..1 ----
#pragma unroll
        for (int mi = 0; mi < 8; ++mi)
            a[mi] = *(const short8*)(lds + base + aoff + mi * 512);
        b0 = *(const short8*)(lds + base + boff);
        b1 = *(const short8*)(lds + base + boff + 512);
        stage(P4 + 7);                        // tile kt+1 B-k1 (other buffer)
        __builtin_amdgcn_sched_barrier(0);
        __builtin_amdgcn_s_barrier();
        asm volatile("s_waitcnt lgkmcnt(0)" ::: "memory");
        __builtin_amdgcn_sched_barrier(0);
        __builtin_amdgcn_s_setprio(1);
#pragma unroll
        for (int mi = 0; mi < 8; ++mi) {
            acc[mi][0] = __builtin_amdgcn_mfma_f32_16x16x32_bf16(a[mi], b0, acc[mi][0], 0, 0, 0);
            acc[mi][1] = __builtin_amdgcn_mfma_f32_16x16x32_bf16(a[mi], b1, acc[mi][1], 0, 0, 0);
        }
        __builtin_amdgcn_s_setprio(0);
        __builtin_amdgcn_sched_barrier(0);
        __builtin_amdgcn_s_barrier();

        // ---- phase 1: ks=0, nj 2..3 (reuse a) ----
        b0 = *(const short8*)(lds + base + boff + 2 * 512);
        b1 = *(const short8*)(lds + base + boff + 3 * 512);
        stage(P4 + 8);                        // tile kt+2 A-k0 (dead since p0)
        __builtin_amdgcn_sched_barrier(0);
        __builtin_amdgcn_s_barrier();
        asm volatile("s_waitcnt lgkmcnt(0)" ::: "memory");
        __builtin_amdgcn_sched_barrier(0);
        __builtin_amdgcn_s_setprio(1);
#pragma unroll
        for (int mi = 0; mi < 8; ++mi) {
            acc[mi][2] = __builtin_amdgcn_mfma_f32_16x16x32_bf16(a[mi], b0, acc[mi][2], 0, 0, 0);
            acc[mi][3] = __builtin_amdgcn_mfma_f32_16x16x32_bf16(a[mi], b1, acc[mi][3], 0, 0, 0);
        }
        __builtin_amdgcn_s_setprio(0);
        __builtin_amdgcn_sched_barrier(0);
        __builtin_amdgcn_s_barrier();

        // ---- phase 2: ks=1, nj 0..1 ----
#pragma unroll
        for (int mi = 0; mi < 8; ++mi)
            a[mi] = *(const short8*)(lds + base + 8192 + aoff + mi * 512);
        b0 = *(const short8*)(lds + base + 8192 + boff);
        b1 = *(const short8*)(lds + base + 8192 + boff + 512);
        stage(P4 + 9);                        // tile kt+2 B-k0 (dead since p1)
        __builtin_amdgcn_sched_barrier(0);
        __builtin_amdgcn_s_barrier();
        asm volatile("s_waitcnt lgkmcnt(0)" ::: "memory");
        __builtin_amdgcn_sched_barrier(0);
        __builtin_amdgcn_s_setprio(1);
#pragma unroll
        for (int mi = 0; mi < 8; ++mi) {
            acc[mi][0] = __builtin_amdgcn_mfma_f32_16x16x32_bf16(a[mi], b0, acc[mi][0], 0, 0, 0);
            acc[mi][1] = __builtin_amdgcn_mfma_f32_16x16x32_bf16(a[mi], b1, acc[mi][1], 0, 0, 0);
        }
        __builtin_amdgcn_s_setprio(0);
        __builtin_amdgcn_sched_barrier(0);
        __builtin_amdgcn_s_barrier();

        // ---- phase 3: ks=1, nj 2..3 (reuse a) ----
        b0 = *(const short8*)(lds + base + 8192 + boff + 2 * 512);
        b1 = *(const short8*)(lds + base + 8192 + boff + 3 * 512);
        stage(P4 + 10);                       // tile kt+2 A-k1 (dead since p2)
        if (kt < 14)       asm volatile("s_waitcnt vmcnt(6)" ::: "memory");
        else if (kt == 14) asm volatile("s_waitcnt vmcnt(0)" ::: "memory");
        __builtin_amdgcn_sched_barrier(0);
        __builtin_amdgcn_s_barrier();         // globalizes the per-wave vmcnt
        asm volatile("s_waitcnt lgkmcnt(0)" ::: "memory");
        __builtin_amdgcn_sched_barrier(0);
        __builtin_amdgcn_s_setprio(1);
#pragma unroll
        for (int mi = 0; mi < 8; ++mi) {
            acc[mi][2] = __builtin_amdgcn_mfma_f32_16x16x32_bf16(a[mi], b0, acc[mi][2], 0, 0, 0);
            acc[mi][3] = __builtin_amdgcn_mfma_f32_16x16x32_bf16(a[mi], b1, acc[mi][3], 0, 0, 0);
        }
        __builtin_amdgcn_s_setprio(0);
        __builtin_amdgcn_sched_barrier(0);
        __builtin_amdgcn_s_barrier();
    }

    // ---- epilogue: registers -> Ht, cached stores (L2 write-combines) ----
    const int cc0 = (z < 3) ? 32 + 64 * z : 64 * (z - 2);
    const int wc = j0 + wn * 64 + l16;
#pragma unroll
    for (int mi = 0; mi < 8; ++mi) {
        int p = (i0 >> 5) + wm * 4 + (mi >> 1);   // slab = b*13 + l
        int b = p / 13, l = p - b * 13;
        int cc = cc0 + (mi & 1) * 16 + quad * 4;
#pragma unroll
        for (int nj = 0; nj < 4; ++nj) {
            int w = wc + nj * 16;
            size_t m = (size_t)b * 13312 + (size_t)w * 13 + l;
            ushort4 pk;
            pk.x = f2b(acc[mi][nj][0]);
            pk.y = f2b(acc[mi][nj][1]);
            pk.z = f2b(acc[mi][nj][2]);
            pk.w = f2b(acc[mi][nj][3]);
            *(ushort4*)(Ht + m * 224 + cc) = pk;
        }
    }
}

// ---------- final conv: y[m,o] = sum_cc Ht[m,cc]*W[o,cc] + bias ----------
// A streamed global->VGPR with depth-2 prefetch; W-only LDS; 4 waves/block
// (ms = m-half of 208 rows, os = o-half of 32 cols) x 1024 blocks
// = 16 waves/CU so TLP hides HBM latency.
__global__ __launch_bounds__(256) void k_fc(const unsigned short* __restrict__ Ht,
                                            const unsigned short* __restrict__ Wb,
                                            const float* __restrict__ bias,
                                            float* __restrict__ y) {
    __shared__ unsigned short sw[64 * 232];
    const int bid = blockIdx.x;               // 1024 = 32 b * 32 vb(32 v)
    const int b = bid >> 5, v0 = (bid & 31) * 32;
    const int t = threadIdx.x;
    const int lane = t & 63, wave = t >> 6;   // 4 waves
    const int ms = wave >> 1, os = wave & 1;
    const int l16 = lane & 15, quad = lane >> 4;

    for (int it = 0; it < 7; ++it) {
        int q = it * 256 + t;                 // 1792 uint4 = 64o x 28sg
        int o = q / 28, sg = q % 28;
        *(uint4*)(sw + o * 232 + sg * 8) = *(const uint4*)(Wb + o * 224 + sg * 8);
    }

    const size_t mw = (size_t)b * 13312 + (size_t)v0 * 13 + ms * 208;
    const unsigned short* ag = Ht + (mw + l16) * 224 + quad * 8;
    float* yb = y + (size_t)b * 851968 + (size_t)v0 * 13 + ms * 208 + quad * 4;

    float bv[2];
#pragma unroll
    for (int nj = 0; nj < 2; ++nj) bv[nj] = bias[os * 32 + nj * 16 + l16];

    short8 c0[7], c1[7];
#pragma unroll
    for (int kk = 0; kk < 7; ++kk) {
        c0[kk] = *(const short8*)(ag + kk * 32);
        c1[kk] = *(const short8*)(ag + 3584 + kk * 32);
    }
    __syncthreads();

    auto body = [&](int mf, short8 (&cur)[7]) {
        short8 nxt[7];
        const bool pf = (mf + 2 < 13);
        if (pf) {
#pragma unroll
            for (int kk = 0; kk < 7; ++kk)
                nxt[kk] = *(const short8*)(ag + (size_t)(mf + 2) * 3584 + kk * 32);
        }
        f32x4 acc[2];
#pragma unroll
        for (int nj = 0; nj < 2; ++nj) acc[nj] = (f32x4){bv[nj], bv[nj], bv[nj], bv[nj]};
#pragma unroll
        for (int kk = 0; kk < 7; ++kk)
#pragma unroll
            for (int nj = 0; nj < 2; ++nj) {
                short8 bf = *(const short8*)(sw + (os * 32 + nj * 16 + l16) * 232 + kk * 32 + quad * 8);
                acc[nj] = __builtin_amdgcn_mfma_f32_16x16x32_bf16(cur[kk], bf, acc[nj], 0, 0, 0);
            }
#pragma unroll
        for (int nj = 0; nj < 2; ++nj)
            *(f32x4*)(yb + (size_t)(os * 32 + nj * 16 + l16) * 13312 + mf * 16) = acc[nj];
        if (pf) {
#pragma unroll
            for (int kk = 0; kk < 7; ++kk) cur[kk] = nxt[kk];
        }
    };
#pragma unroll
    for (int mf = 0; mf < 13; ++mf) {
        if (mf & 1) body(mf, c1); else body(mf, c0);
    }
}

extern "C" void kernel_launch(void* const* d_in, const int* in_sizes, int n_in,
                              void* d_out, int out_size, void* d_ws, size_t ws_size,
                              hipStream_t stream) {
    const float* x    = (const float*)d_in[0];
    const float* A0   = (const float*)d_in[1];
    const float* A1   = (const float*)d_in[2];
    const float* A2   = (const float*)d_in[3];
    const float* W    = (const float*)d_in[4];
    const float* bias = (const float*)d_in[5];

    if (ws_size < WS_NEED) return;

    unsigned short* Ht = (unsigned short*)d_ws;
    unsigned short* AT = (unsigned short*)((char*)d_ws + OFF_AT);
    unsigned short* Wb = (unsigned short*)((char*)d_ws + OFF_WB);
    unsigned short* Tarena = (unsigned short*)d_out;   // block0: x-T
    unsigned short* Abf = Tarena + SZE;                // arena block1 (free)
    unsigned short* AT2 = Tarena + 2 * SZE;            // arena block2 (free)

    k_prep<<<512, 256, 0, stream>>>(x, Tarena, Ht);
    k_prep_A<<<dim3(32, 32, 3), 256, 0, stream>>>(A0, A1, A2, AT, Abf);
    k_prep_W<<<56, 256, 0, stream>>>(W, Wb);
    // AT2[w,v] = sum_u AT[w,u]*Abf[v,u] = (A*A)^T, bf16
    k_gemm<<<dim3(8, 8, 3), 256, 0, stream>>>(AT, 1048576L, Abf, Abf,
                                              AT2, 1048576L, nullptr, 1);
    // all 6 hops from x-T; i0-major dispatch (x = 24 (j0,z) combos, y = i0)
    k_gemm256<<<dim3(24, 52, 1), 512, 0, stream>>>(Tarena, AT, AT2, Ht);
    k_fc<<<1024, 256, 0, stream>>>(Ht, Wb, bias, (float*)d_out);
}